// Round 18
// baseline (61.848 us; speedup 1.0000x reference)
//
#include <hip/hip_runtime.h>
#include <hip/hip_bf16.h>
#include <math.h>

#define BSZ   128
#define NP    16
#define NC    21
#define NH    256
#define HOUT  16
#define NFLAT 5376     // K (permuted layout k' = p*336 + c*16 + wo)

// fused-kernel geometry: block (bm, sk): 32 rows (b = 2bm,2bm+1), K-slice 672
#define XT_STRIDE 680                      // ushorts (672 + 8 pad)
#define XT_BYTES  (32 * XT_STRIDE * 2)     // 43520 -> 2 blocks/CU
#define PSTR      (2048 * 256)             // part per-sk stride (f32)

typedef __attribute__((ext_vector_type(4))) float f32x4;
typedef __attribute__((ext_vector_type(2))) float f32x2;
typedef __attribute__((ext_vector_type(8))) short bf16x8;

__device__ __forceinline__ ushort f2bf(float v) {
    __hip_bfloat16 h = __float2bfloat16(v);
    return *reinterpret_cast<ushort*>(&h);
}

// tanh(0.01*ln(s)) via odd poly: u in [-0.23, 0.03]; err < 2e-6
__device__ __forceinline__ float hist_act(float s) {
    float u = 0.01f * __logf(fmaxf(s, 1e-10f));
    float u2 = u * u;
    return u * (1.f + u2 * (-0.33333333f + 0.13333333f * u2));
}

// tanh(x) = 1 - 2/(e^{2x}+1)
__device__ __forceinline__ float fast_tanh(float v) {
    float e = __expf(2.f * v);
    return 1.f - 2.f * __builtin_amdgcn_rcpf(e + 1.f);
}

// ---------------------------------------------------------------------------
// Kernel 1 (fused): [blocks 0..167: WtF prep (4 units each)] -> RBF
//                   -> gate(cnt==168) -> GEMM (A: LDS xT, B: global WtF).
// 512 blocks (bm = bid>>3, sk = bid&7) x 1024 thr, 43.5 KB LDS, 2 blocks/CU.
// WtF fragment-major: chunk id covers n = ((id>>6)&15)*16 + (l&15),
//   k' = (id>>10)*32 + (l>>4)*8 + e  (per-element p/c decode, OOB-safe).
// ---------------------------------------------------------------------------
extern "C" __global__ __launch_bounds__(1024, 8) void k_fused(
    const float* __restrict__ sim,     // [128][16][64][64]
    const float* __restrict__ W,       // [5376][256] fp32
    ushort* __restrict__ WtF,          // fragment-major, 2.75MB
    float* __restrict__ part,          // [8][2048][256]
    uint* __restrict__ cnt)            // [1] zeroed per launch
{
    extern __shared__ __align__(16) char smem[];
    ushort* xT = (ushort*)smem;                       // [32][XT_STRIDE]
    const int bid = blockIdx.x;
    const int bm = bid >> 3, sk = bid & 7;
    const int tid = threadIdx.x;

    // ================= PHASE 0: WtF prep (blocks 0..167) ===================
    if (bid < 168) {
        int id = bid * 1024 + tid;                 // [0, 172032)
        int l = id & 63;
        int ks = id >> 10;                         // [0, 168)
        int n = (((id >> 6) & 15) << 4) + (l & 15);
        int kb = ks * 32 + (l >> 4) * 8;
        ushort v[8];
#pragma unroll
        for (int e = 0; e < 8; ++e) {
            int kp = kb + e;                       // k' in [0, 5376)
            int p = kp / 336;
            int rem = kp - p * 336;
            int c = rem >> 4, wo = rem & 15;
            int ksrc = c * 256 + p * 16 + wo;      // original W row
            v[e] = f2bf(W[(size_t)ksrc * NH + n]);
        }
        *(uint4*)(WtF + (size_t)id * 8) = *(uint4*)v;

        __syncthreads();   // drain stores (waitcnt before barrier)
        if (tid == 0)
            __hip_atomic_fetch_add(cnt, 1u, __ATOMIC_RELEASE, __HIP_MEMORY_SCOPE_AGENT);
    }

    // ================= PHASE A: RBF (1 task/thread, packed f32) ============
    {
        int w = tid >> 6, l = tid & 63;
        int tile = w >> 2, q = w & 3;                // 4 sim tiles, ho-quad q
        int boff = tile >> 1, poff = tile & 1;
        int wo = l & 15, ho = q * 4 + (l >> 4);

        const float* src = sim
            + (((size_t)(2 * bm + boff)) * 16 + (2 * sk + poff)) * 4096
            + (size_t)(ho * 4) * 64 + wo * 4;
        float4 ebuf[4];
#pragma unroll
        for (int i = 0; i < 4; ++i) ebuf[i] = *(const float4*)(src + i * 64);

        f32x2 f2a[8], g2a[8];
        float s0[4];
#pragma unroll
        for (int i = 0; i < 4; ++i) {
            float4 e4 = ebuf[i];
            float pa = 0.f, pb = 0.f;
#pragma unroll
            for (int jj = 0; jj < 4; ++jj) {
                float e = (jj == 0) ? e4.x : (jj == 1) ? e4.y : (jj == 2) ? e4.z : e4.w;
                float d0 = e - 1.0f;
                float t0 = __expf(-50.f * d0 * d0);
                if (jj & 1) pb += t0; else pa += t0;
                float d1 = e - 0.95f;
                float fv = __expf(-50.f * d1 * d1);
                float gv = __expf(-10.f * d1 - 0.5f);
                int k2 = i * 4 + jj;
                if (k2 & 1) { f2a[k2 >> 1].y = fv; g2a[k2 >> 1].y = gv; }
                else        { f2a[k2 >> 1].x = fv; g2a[k2 >> 1].x = gv; }
            }
            s0[i] = pa + pb;
        }
        float sum0 = (s0[0] + s0[1]) + (s0[2] + s0[3]);
        ushort* xrow = xT + (boff * 16 + ho) * XT_STRIDE + poff * 336 + wo;
        xrow[0] = f2bf(hist_act(sum0));

        const f32x2 E2 = {0.36787944117f, 0.36787944117f};
#pragma unroll
        for (int c = 1; c < 21; ++c) {
            // packed tree: 7 pk_add + 1 scalar add
            f32x2 t0 = f2a[0] + f2a[1], t1 = f2a[2] + f2a[3];
            f32x2 t2 = f2a[4] + f2a[5], t3 = f2a[6] + f2a[7];
            f32x2 u0 = t0 + t1, u1 = t2 + t3;
            f32x2 vv = u0 + u1;
            float sv = vv.x + vv.y;
            xrow[c * 16] = f2bf(hist_act(sv));
            if (c < 20) {
#pragma unroll
                for (int k2 = 0; k2 < 8; ++k2) { f2a[k2] *= g2a[k2]; g2a[k2] *= E2; }
            }
        }
    }
    __syncthreads();   // xT complete

    // ================= gate: WtF ready (free in steady state) ==============
    if (tid == 0) {
        while (__hip_atomic_load(cnt, __ATOMIC_ACQUIRE, __HIP_MEMORY_SCOPE_AGENT) < 168u)
            __builtin_amdgcn_s_sleep(2);
    }
    __syncthreads();

    // ================= PHASE B: GEMM (A: LDS, B: global; no barriers) ======
    {
        int l = tid & 63, w = tid >> 6;
        int wr = w >> 3, wc = w & 7;                // 2x8 waves; wave tile 16x32
        int lr = l & 15, lk = l >> 4;
        int arow = wr * 16 + lr;
        const char* aBase = (const char*)xT + arow * (XT_STRIDE * 2);

        // B fragment base: nt16 = wc*2 + nt
        const ushort* gB = WtF + (((size_t)(sk * 21) * 16 + wc * 2) * 64 + l) * 8;

        f32x4 acc[2];
        acc[0] = (f32x4){0.f, 0.f, 0.f, 0.f};
        acc[1] = (f32x4){0.f, 0.f, 0.f, 0.f};

#pragma unroll
        for (int kt = 0; kt < 21; ++kt) {
            bf16x8 a = *(const bf16x8*)(aBase + kt * 64 + lk * 16);
#pragma unroll
            for (int nt = 0; nt < 2; ++nt) {
                bf16x8 bb = *(const bf16x8*)(gB + ((size_t)kt * 16 + nt) * 512);
                acc[nt] = __builtin_amdgcn_mfma_f32_16x16x32_bf16(a, bb, acc[nt], 0, 0, 0);
            }
        }

        // store partials: C row=(l>>4)*4+j, col=l&15
        float* pp = part + (size_t)sk * PSTR;
        int crow = bm * 32 + wr * 16 + lk * 4;
#pragma unroll
        for (int nt = 0; nt < 2; ++nt) {
            int ccol = wc * 32 + nt * 16 + lr;
#pragma unroll
            for (int j = 0; j < 4; ++j)
                pp[(size_t)(crow + j) * 256 + ccol] = acc[nt][j];
        }
    }
}

// ---------------------------------------------------------------------------
// Kernel 2: split-K reduce + bias + tanh + attention + heads. 128 x 512 thr.
// (r17-identical)
// ---------------------------------------------------------------------------
__global__ __launch_bounds__(512) void k_head(
    const float* __restrict__ part,    // [8][2048][256]
    const float* __restrict__ b_flat,
    const float* __restrict__ f_add,
    const float* __restrict__ W_attn,
    const float* __restrict__ b_attn,
    const float* __restrict__ W_fadd,
    const float* __restrict__ b_fadd,
    const float* __restrict__ W_d1,
    const float* __restrict__ b_d1,
    const float* __restrict__ W_d2,
    const float* __restrict__ b_d2,
    const float* __restrict__ wfeat,
    float* __restrict__ out)           // [512]
{
    const int b = blockIdx.x;
    const int tid = threadIdx.x;

    __shared__ float sh1[16 * 256];
    __shared__ float slog[16];
    __shared__ float scomb[256];
    __shared__ float scpart[512];
    __shared__ float r01[8];

#pragma unroll
    for (int i = 0; i < 8; ++i) {
        int idx = i * 512 + tid;
        int row = idx >> 8, col = idx & 255;
        size_t prow = (size_t)(b * 16 + row) * 256 + col;
        float v = b_flat[col];
#pragma unroll
        for (int s = 0; s < 8; ++s) v += part[(size_t)s * PSTR + prow];
        sh1[idx] = fast_tanh(v);
    }
    __syncthreads();

    if (tid < 256) {
        int ho = tid >> 4, j = tid & 15;
        float sv = 0.f;
#pragma unroll
        for (int t2 = 0; t2 < 16; ++t2)
            sv += sh1[ho * 256 + j + t2 * 16] * W_attn[j + t2 * 16];
        sv += __shfl_xor(sv, 1); sv += __shfl_xor(sv, 2);
        sv += __shfl_xor(sv, 4); sv += __shfl_xor(sv, 8);
        if (j == 0) slog[ho] = sv + b_attn[0];
    }
    __syncthreads();

    if (tid < 256) {
        float attnv[16];
        float mx = -1e30f;
#pragma unroll
        for (int t2 = 0; t2 < 16; ++t2) mx = fmaxf(mx, slog[t2]);
        float sum = 0.f;
#pragma unroll
        for (int t2 = 0; t2 < 16; ++t2) { attnv[t2] = __expf(slog[t2] - mx); sum += attnv[t2]; }
        float inv = __builtin_amdgcn_rcpf(sum);

        float lc = 0.f;
#pragma unroll
        for (int t2 = 0; t2 < 16; ++t2) lc += attnv[t2] * inv * sh1[t2 * 256 + tid];
        lc = fast_tanh(lc);

        float fp = b_fadd[tid];
#pragma unroll
        for (int k = 0; k < 17; ++k) fp += f_add[b * 17 + k] * W_fadd[k * 256 + tid];
        fp = fast_tanh(fp);

        float sg = __builtin_amdgcn_rcpf(1.f + __expf(-wfeat[0]));
        scomb[tid] = (1.f - sg) * fp + sg * lc;
    }
    __syncthreads();

    {
        int n = tid & 255, half = tid >> 8;
        float sc = 0.f;
        int k0 = half * 128;
#pragma unroll 8
        for (int k = 0; k < 128; ++k) sc += scomb[k0 + k] * W_d1[(k0 + k) * 256 + n];
        scpart[half * 256 + n] = sc;
    }
    __syncthreads();

    if (tid < 256) {
        float sc = fast_tanh(scpart[tid] + scpart[256 + tid] + b_d1[tid]);
        float p0 = sc * W_d2[tid * 2 + 0];
        float p1 = sc * W_d2[tid * 2 + 1];
#pragma unroll
        for (int off = 1; off < 64; off <<= 1) {
            p0 += __shfl_xor(p0, off);
            p1 += __shfl_xor(p1, off);
        }
        if ((tid & 63) == 0) { r01[tid >> 6] = p0; r01[4 + (tid >> 6)] = p1; }
    }
    __syncthreads();

    if (tid == 0) {
        float o0 = r01[0] + r01[1] + r01[2] + r01[3] + b_d2[0];
        float o1 = r01[4] + r01[5] + r01[6] + r01[7] + b_d2[1];
        float mx = fmaxf(o0, o1);
        float lse = mx + __logf(__expf(o0 - mx) + __expf(o1 - mx));
        out[b * 2 + 0] = o0 - lse;
        out[b * 2 + 1] = o1 - lse;
        out[256 + b * 2 + 0] = o0;
        out[256 + b * 2 + 1] = o1;
    }
}

// ---------------------------------------------------------------------------
extern "C" void kernel_launch(void* const* d_in, const int* in_sizes, int n_in,
                              void* d_out, int out_size, void* d_ws, size_t ws_size,
                              hipStream_t stream) {
    const float* sim    = (const float*)d_in[0];
    const float* f_add  = (const float*)d_in[1];
    const float* W_flat = (const float*)d_in[2];
    const float* b_flat = (const float*)d_in[3];
    const float* W_attn = (const float*)d_in[4];
    const float* b_attn = (const float*)d_in[5];
    const float* W_fadd = (const float*)d_in[6];
    const float* b_fadd = (const float*)d_in[7];
    const float* W_d1   = (const float*)d_in[8];
    const float* b_d1   = (const float*)d_in[9];
    const float* W_d2   = (const float*)d_in[10];
    const float* b_d2   = (const float*)d_in[11];
    const float* wfeat  = (const float*)d_in[12];
    float* out = (float*)d_out;

    ushort* WtF = (ushort*)d_ws;                        // 2.75MB fragment-major
    float* part = (float*)(WtF + (size_t)256 * NFLAT);  // [8][2048][256] f32 (16.8MB)
    uint* cnt = (uint*)((char*)d_ws + (36u << 20));     // 1 counter @36MB

    hipMemsetAsync(cnt, 0, sizeof(uint), stream);
    hipLaunchKernelGGL(k_fused, dim3(512), dim3(1024), XT_BYTES, stream,
                       sim, W_flat, WtF, part, cnt);
    hipLaunchKernelGGL(k_head, dim3(128), dim3(512), 0, stream,
                       part, b_flat, f_add, W_attn, b_attn, W_fadd, b_fadd,
                       W_d1, b_d1, W_d2, b_d2, wfeat, out);
}

// Round 19
// 45.454 us; speedup vs baseline: 1.3607x; 1.3607x over previous
//
#include <hip/hip_runtime.h>
#include <hip/hip_bf16.h>
#include <math.h>

#define BSZ   128
#define NP    16
#define NC    21
#define NH    256
#define HOUT  16
#define NFLAT 5376     // K (permuted layout k' = p*336 + c*16 + wo)

// fused-kernel geometry: block (bm, sk): 32 rows (b = 2bm,2bm+1), K-slice 672
#define XT_STRIDE 680                      // ushorts (672 + 8 pad)
#define XT_BYTES  (32 * XT_STRIDE * 2)     // 43520 -> 2 blocks/CU
#define PSTR      (2048 * 256)             // part per-sk stride (elements)

typedef __attribute__((ext_vector_type(4))) float f32x4;
typedef __attribute__((ext_vector_type(2))) float f32x2;
typedef __attribute__((ext_vector_type(8))) short bf16x8;

__device__ __forceinline__ ushort f2bf(float v) {
    __hip_bfloat16 h = __float2bfloat16(v);
    return *reinterpret_cast<ushort*>(&h);
}

__device__ __forceinline__ float bf2f(ushort u) {
    union { uint i; float f; } cv;
    cv.i = ((uint)u) << 16;
    return cv.f;
}

// tanh(0.01*ln(s)) via odd poly: u in [-0.23, 0.03]; err < 2e-6
__device__ __forceinline__ float hist_act(float s) {
    float u = 0.01f * __logf(fmaxf(s, 1e-10f));
    float u2 = u * u;
    return u * (1.f + u2 * (-0.33333333f + 0.13333333f * u2));
}

// tanh(x) = 1 - 2/(e^{2x}+1)
__device__ __forceinline__ float fast_tanh(float v) {
    float e = __expf(2.f * v);
    return 1.f - 2.f * __builtin_amdgcn_rcpf(e + 1.f);
}

// ---------------------------------------------------------------------------
// Kernel 0: WtF fragment-major B. chunk id = (ks*16 + nt16)*64 + lane covers
//   n = nt16*16 + (l&15), k' = ks*32 + (l>>4)*8 + e  (per-element p/c decode).
// 672 blocks x 256 thr.  (r17-identical)
// ---------------------------------------------------------------------------
__global__ __launch_bounds__(256) void k_prep(const float* __restrict__ W,
                                              ushort* __restrict__ WtF) {
    int id = blockIdx.x * 256 + threadIdx.x;   // [0, 172032)
    int l = id & 63;
    int ks = id >> 10;                         // [0, 168)
    int n = (((id >> 6) & 15) << 4) + (l & 15);
    int kb = ks * 32 + (l >> 4) * 8;
    ushort v[8];
#pragma unroll
    for (int e = 0; e < 8; ++e) {
        int kp = kb + e;                       // k' in [0, 5376)
        int p = kp / 336;
        int rem = kp - p * 336;
        int c = rem >> 4, wo = rem & 15;
        int ksrc = c * 256 + p * 16 + wo;      // original W row
        v[e] = f2bf(W[(size_t)ksrc * NH + n]);
    }
    *(uint4*)(WtF + (size_t)id * 8) = *(uint4*)v;
}

// ---------------------------------------------------------------------------
// Kernel 1 (fused): RBF (packed-f32) -> 1 barrier -> GEMM (A: LDS, B: global).
// 512 blocks (bm = bid>>3, sk = bid&7) x 1024 thr, 43.5 KB LDS, 2 blocks/CU.
// (r17 structure; only change: partials stored as bf16)
// ---------------------------------------------------------------------------
extern "C" __global__ __launch_bounds__(1024, 8) void k_fused(
    const float* __restrict__ sim,     // [128][16][64][64]
    const ushort* __restrict__ WtF,    // fragment-major
    ushort* __restrict__ part)         // [8][2048][256] bf16
{
    extern __shared__ __align__(16) char smem[];
    ushort* xT = (ushort*)smem;                       // [32][XT_STRIDE]
    const int bid = blockIdx.x;
    const int bm = bid >> 3, sk = bid & 7;
    const int tid = threadIdx.x;

    // ================= PHASE A: RBF (1 task/thread, packed f32) ============
    {
        int w = tid >> 6, l = tid & 63;
        int tile = w >> 2, q = w & 3;                // 4 sim tiles, ho-quad q
        int boff = tile >> 1, poff = tile & 1;
        int wo = l & 15, ho = q * 4 + (l >> 4);

        const float* src = sim
            + (((size_t)(2 * bm + boff)) * 16 + (2 * sk + poff)) * 4096
            + (size_t)(ho * 4) * 64 + wo * 4;
        float4 ebuf[4];
#pragma unroll
        for (int i = 0; i < 4; ++i) ebuf[i] = *(const float4*)(src + i * 64);

        f32x2 f2a[8], g2a[8];
        float s0[4];
#pragma unroll
        for (int i = 0; i < 4; ++i) {
            float4 e4 = ebuf[i];
            float pa = 0.f, pb = 0.f;
#pragma unroll
            for (int jj = 0; jj < 4; ++jj) {
                float e = (jj == 0) ? e4.x : (jj == 1) ? e4.y : (jj == 2) ? e4.z : e4.w;
                float d0 = e - 1.0f;
                float t0 = __expf(-50.f * d0 * d0);
                if (jj & 1) pb += t0; else pa += t0;
                float d1 = e - 0.95f;
                float fv = __expf(-50.f * d1 * d1);
                float gv = __expf(-10.f * d1 - 0.5f);
                int k2 = i * 4 + jj;
                if (k2 & 1) { f2a[k2 >> 1].y = fv; g2a[k2 >> 1].y = gv; }
                else        { f2a[k2 >> 1].x = fv; g2a[k2 >> 1].x = gv; }
            }
            s0[i] = pa + pb;
        }
        float sum0 = (s0[0] + s0[1]) + (s0[2] + s0[3]);
        ushort* xrow = xT + (boff * 16 + ho) * XT_STRIDE + poff * 336 + wo;
        xrow[0] = f2bf(hist_act(sum0));

        const f32x2 E2 = {0.36787944117f, 0.36787944117f};
#pragma unroll
        for (int c = 1; c < 21; ++c) {
            f32x2 t0 = f2a[0] + f2a[1], t1 = f2a[2] + f2a[3];
            f32x2 t2 = f2a[4] + f2a[5], t3 = f2a[6] + f2a[7];
            f32x2 u0 = t0 + t1, u1 = t2 + t3;
            f32x2 vv = u0 + u1;
            float sv = vv.x + vv.y;
            xrow[c * 16] = f2bf(hist_act(sv));
            if (c < 20) {
#pragma unroll
                for (int k2 = 0; k2 < 8; ++k2) { f2a[k2] *= g2a[k2]; g2a[k2] *= E2; }
            }
        }
    }
    __syncthreads();   // xT complete

    // ================= PHASE B: GEMM (A: LDS, B: global; no barriers) ======
    {
        int l = tid & 63, w = tid >> 6;
        int wr = w >> 3, wc = w & 7;                // 2x8 waves; wave tile 16x32
        int lr = l & 15, lk = l >> 4;
        int arow = wr * 16 + lr;
        const char* aBase = (const char*)xT + arow * (XT_STRIDE * 2);

        const ushort* gB = WtF + (((size_t)(sk * 21) * 16 + wc * 2) * 64 + l) * 8;

        f32x4 acc[2];
        acc[0] = (f32x4){0.f, 0.f, 0.f, 0.f};
        acc[1] = (f32x4){0.f, 0.f, 0.f, 0.f};

#pragma unroll
        for (int kt = 0; kt < 21; ++kt) {
            bf16x8 a = *(const bf16x8*)(aBase + kt * 64 + lk * 16);
#pragma unroll
            for (int nt = 0; nt < 2; ++nt) {
                bf16x8 bb = *(const bf16x8*)(gB + ((size_t)kt * 16 + nt) * 512);
                acc[nt] = __builtin_amdgcn_mfma_f32_16x16x32_bf16(a, bb, acc[nt], 0, 0, 0);
            }
        }

        // store partials (bf16): C row=(l>>4)*4+j, col=l&15
        ushort* pp = part + (size_t)sk * PSTR;
        int crow = bm * 32 + wr * 16 + lk * 4;
#pragma unroll
        for (int nt = 0; nt < 2; ++nt) {
            int ccol = wc * 32 + nt * 16 + lr;
#pragma unroll
            for (int j = 0; j < 4; ++j)
                pp[(size_t)(crow + j) * 256 + ccol] = f2bf(acc[nt][j]);
        }
    }
}

// ---------------------------------------------------------------------------
// Kernel 2: split-K reduce (bf16 part) + bias + tanh + attention + heads.
// 128 x 512 thr. (r17 body; only part dtype changed)
// ---------------------------------------------------------------------------
__global__ __launch_bounds__(512) void k_head(
    const ushort* __restrict__ part,   // [8][2048][256] bf16
    const float* __restrict__ b_flat,
    const float* __restrict__ f_add,
    const float* __restrict__ W_attn,
    const float* __restrict__ b_attn,
    const float* __restrict__ W_fadd,
    const float* __restrict__ b_fadd,
    const float* __restrict__ W_d1,
    const float* __restrict__ b_d1,
    const float* __restrict__ W_d2,
    const float* __restrict__ b_d2,
    const float* __restrict__ wfeat,
    float* __restrict__ out)           // [512]
{
    const int b = blockIdx.x;
    const int tid = threadIdx.x;

    __shared__ float sh1[16 * 256];
    __shared__ float slog[16];
    __shared__ float scomb[256];
    __shared__ float scpart[512];
    __shared__ float r01[8];

#pragma unroll
    for (int i = 0; i < 8; ++i) {
        int idx = i * 512 + tid;
        int row = idx >> 8, col = idx & 255;
        size_t prow = (size_t)(b * 16 + row) * 256 + col;
        float v = b_flat[col];
#pragma unroll
        for (int s = 0; s < 8; ++s) v += bf2f(part[(size_t)s * PSTR + prow]);
        sh1[idx] = fast_tanh(v);
    }
    __syncthreads();

    if (tid < 256) {
        int ho = tid >> 4, j = tid & 15;
        float sv = 0.f;
#pragma unroll
        for (int t2 = 0; t2 < 16; ++t2)
            sv += sh1[ho * 256 + j + t2 * 16] * W_attn[j + t2 * 16];
        sv += __shfl_xor(sv, 1); sv += __shfl_xor(sv, 2);
        sv += __shfl_xor(sv, 4); sv += __shfl_xor(sv, 8);
        if (j == 0) slog[ho] = sv + b_attn[0];
    }
    __syncthreads();

    if (tid < 256) {
        float attnv[16];
        float mx = -1e30f;
#pragma unroll
        for (int t2 = 0; t2 < 16; ++t2) mx = fmaxf(mx, slog[t2]);
        float sum = 0.f;
#pragma unroll
        for (int t2 = 0; t2 < 16; ++t2) { attnv[t2] = __expf(slog[t2] - mx); sum += attnv[t2]; }
        float inv = __builtin_amdgcn_rcpf(sum);

        float lc = 0.f;
#pragma unroll
        for (int t2 = 0; t2 < 16; ++t2) lc += attnv[t2] * inv * sh1[t2 * 256 + tid];
        lc = fast_tanh(lc);

        float fp = b_fadd[tid];
#pragma unroll
        for (int k = 0; k < 17; ++k) fp += f_add[b * 17 + k] * W_fadd[k * 256 + tid];
        fp = fast_tanh(fp);

        float sg = __builtin_amdgcn_rcpf(1.f + __expf(-wfeat[0]));
        scomb[tid] = (1.f - sg) * fp + sg * lc;
    }
    __syncthreads();

    {
        int n = tid & 255, half = tid >> 8;
        float sc = 0.f;
        int k0 = half * 128;
#pragma unroll 8
        for (int k = 0; k < 128; ++k) sc += scomb[k0 + k] * W_d1[(k0 + k) * 256 + n];
        scpart[half * 256 + n] = sc;
    }
    __syncthreads();

    if (tid < 256) {
        float sc = fast_tanh(scpart[tid] + scpart[256 + tid] + b_d1[tid]);
        float p0 = sc * W_d2[tid * 2 + 0];
        float p1 = sc * W_d2[tid * 2 + 1];
#pragma unroll
        for (int off = 1; off < 64; off <<= 1) {
            p0 += __shfl_xor(p0, off);
            p1 += __shfl_xor(p1, off);
        }
        if ((tid & 63) == 0) { r01[tid >> 6] = p0; r01[4 + (tid >> 6)] = p1; }
    }
    __syncthreads();

    if (tid == 0) {
        float o0 = r01[0] + r01[1] + r01[2] + r01[3] + b_d2[0];
        float o1 = r01[4] + r01[5] + r01[6] + r01[7] + b_d2[1];
        float mx = fmaxf(o0, o1);
        float lse = mx + __logf(__expf(o0 - mx) + __expf(o1 - mx));
        out[b * 2 + 0] = o0 - lse;
        out[b * 2 + 1] = o1 - lse;
        out[256 + b * 2 + 0] = o0;
        out[256 + b * 2 + 1] = o1;
    }
}

// ---------------------------------------------------------------------------
extern "C" void kernel_launch(void* const* d_in, const int* in_sizes, int n_in,
                              void* d_out, int out_size, void* d_ws, size_t ws_size,
                              hipStream_t stream) {
    const float* sim    = (const float*)d_in[0];
    const float* f_add  = (const float*)d_in[1];
    const float* W_flat = (const float*)d_in[2];
    const float* b_flat = (const float*)d_in[3];
    const float* W_attn = (const float*)d_in[4];
    const float* b_attn = (const float*)d_in[5];
    const float* W_fadd = (const float*)d_in[6];
    const float* b_fadd = (const float*)d_in[7];
    const float* W_d1   = (const float*)d_in[8];
    const float* b_d1   = (const float*)d_in[9];
    const float* W_d2   = (const float*)d_in[10];
    const float* b_d2   = (const float*)d_in[11];
    const float* wfeat  = (const float*)d_in[12];
    float* out = (float*)d_out;

    ushort* WtF  = (ushort*)d_ws;                        // 2.75MB fragment-major
    ushort* part = WtF + (size_t)256 * NFLAT;            // [8][2048][256] bf16 (8.4MB)

    hipLaunchKernelGGL(k_prep, dim3(672), dim3(256), 0, stream, W_flat, WtF);
    hipLaunchKernelGGL(k_fused, dim3(512), dim3(1024), XT_BYTES, stream, sim, WtF, part);
    hipLaunchKernelGGL(k_head, dim3(128), dim3(512), 0, stream,
                       part, b_flat, f_add, W_attn, b_attn, W_fadd, b_fadd,
                       W_d1, b_d1, W_d2, b_d2, wfeat, out);
}

// Round 20
// 45.115 us; speedup vs baseline: 1.3709x; 1.0075x over previous
//
#include <hip/hip_runtime.h>
#include <hip/hip_bf16.h>
#include <math.h>

#define BSZ   128
#define NP    16
#define NC    21
#define NH    256
#define HOUT  16
#define NFLAT 5376     // K (permuted layout k' = p*336 + c*16 + wo)

// fused-kernel geometry: block (bm, sk): 32 rows (b = 2bm,2bm+1), K-slice 672
#define XT_STRIDE 680                      // ushorts (672 + 8 pad)
#define XT_BYTES  (32 * XT_STRIDE * 2)     // 43520 -> 2 blocks/CU
#define PSTR      (2048 * 256)             // part per-sk stride (elements)

typedef __attribute__((ext_vector_type(4))) float f32x4;
typedef __attribute__((ext_vector_type(2))) float f32x2;
typedef __attribute__((ext_vector_type(8))) short bf16x8;

__device__ __forceinline__ ushort f2bf(float v) {
    __hip_bfloat16 h = __float2bfloat16(v);
    return *reinterpret_cast<ushort*>(&h);
}

__device__ __forceinline__ float bf2f(ushort u) {
    union { uint i; float f; } cv;
    cv.i = ((uint)u) << 16;
    return cv.f;
}

// tanh(0.01*ln(s)) via odd poly: u in [-0.23, 0.03]; err < 2e-6
__device__ __forceinline__ float hist_act(float s) {
    float u = 0.01f * __logf(fmaxf(s, 1e-10f));
    float u2 = u * u;
    return u * (1.f + u2 * (-0.33333333f + 0.13333333f * u2));
}

// tanh(x) = 1 - 2/(e^{2x}+1)
__device__ __forceinline__ float fast_tanh(float v) {
    float e = __expf(2.f * v);
    return 1.f - 2.f * __builtin_amdgcn_rcpf(e + 1.f);
}

// ---------------------------------------------------------------------------
// Kernel 0: WtF fragment-major B. chunk id = (ks*16 + nt16)*64 + lane covers
//   n = nt16*16 + (l&15), k' = ks*32 + (l>>4)*8 + e  (per-element p/c decode).
// 672 blocks x 256 thr.  (r19-identical)
// ---------------------------------------------------------------------------
__global__ __launch_bounds__(256) void k_prep(const float* __restrict__ W,
                                              ushort* __restrict__ WtF) {
    int id = blockIdx.x * 256 + threadIdx.x;   // [0, 172032)
    int l = id & 63;
    int ks = id >> 10;                         // [0, 168)
    int n = (((id >> 6) & 15) << 4) + (l & 15);
    int kb = ks * 32 + (l >> 4) * 8;
    ushort v[8];
#pragma unroll
    for (int e = 0; e < 8; ++e) {
        int kp = kb + e;                       // k' in [0, 5376)
        int p = kp / 336;
        int rem = kp - p * 336;
        int c = rem >> 4, wo = rem & 15;
        int ksrc = c * 256 + p * 16 + wo;      // original W row
        v[e] = f2bf(W[(size_t)ksrc * NH + n]);
    }
    *(uint4*)(WtF + (size_t)id * 8) = *(uint4*)v;
}

// ---------------------------------------------------------------------------
// Kernel 1 (fused): RBF (packed-f32) -> 1 barrier -> GEMM (A: LDS, B: global).
// 512 blocks (bm = bid>>3, sk = bid&7) x 1024 thr, 43.5 KB LDS, 2 blocks/CU.
// (r19-identical)
// ---------------------------------------------------------------------------
extern "C" __global__ __launch_bounds__(1024, 8) void k_fused(
    const float* __restrict__ sim,     // [128][16][64][64]
    const ushort* __restrict__ WtF,    // fragment-major
    ushort* __restrict__ part)         // [8][2048][256] bf16
{
    extern __shared__ __align__(16) char smem[];
    ushort* xT = (ushort*)smem;                       // [32][XT_STRIDE]
    const int bid = blockIdx.x;
    const int bm = bid >> 3, sk = bid & 7;
    const int tid = threadIdx.x;

    // ================= PHASE A: RBF (1 task/thread, packed f32) ============
    {
        int w = tid >> 6, l = tid & 63;
        int tile = w >> 2, q = w & 3;                // 4 sim tiles, ho-quad q
        int boff = tile >> 1, poff = tile & 1;
        int wo = l & 15, ho = q * 4 + (l >> 4);

        const float* src = sim
            + (((size_t)(2 * bm + boff)) * 16 + (2 * sk + poff)) * 4096
            + (size_t)(ho * 4) * 64 + wo * 4;
        float4 ebuf[4];
#pragma unroll
        for (int i = 0; i < 4; ++i) ebuf[i] = *(const float4*)(src + i * 64);

        f32x2 f2a[8], g2a[8];
        float s0[4];
#pragma unroll
        for (int i = 0; i < 4; ++i) {
            float4 e4 = ebuf[i];
            float pa = 0.f, pb = 0.f;
#pragma unroll
            for (int jj = 0; jj < 4; ++jj) {
                float e = (jj == 0) ? e4.x : (jj == 1) ? e4.y : (jj == 2) ? e4.z : e4.w;
                float d0 = e - 1.0f;
                float t0 = __expf(-50.f * d0 * d0);
                if (jj & 1) pb += t0; else pa += t0;
                float d1 = e - 0.95f;
                float fv = __expf(-50.f * d1 * d1);
                float gv = __expf(-10.f * d1 - 0.5f);
                int k2 = i * 4 + jj;
                if (k2 & 1) { f2a[k2 >> 1].y = fv; g2a[k2 >> 1].y = gv; }
                else        { f2a[k2 >> 1].x = fv; g2a[k2 >> 1].x = gv; }
            }
            s0[i] = pa + pb;
        }
        float sum0 = (s0[0] + s0[1]) + (s0[2] + s0[3]);
        ushort* xrow = xT + (boff * 16 + ho) * XT_STRIDE + poff * 336 + wo;
        xrow[0] = f2bf(hist_act(sum0));

        const f32x2 E2 = {0.36787944117f, 0.36787944117f};
#pragma unroll
        for (int c = 1; c < 21; ++c) {
            f32x2 t0 = f2a[0] + f2a[1], t1 = f2a[2] + f2a[3];
            f32x2 t2 = f2a[4] + f2a[5], t3 = f2a[6] + f2a[7];
            f32x2 u0 = t0 + t1, u1 = t2 + t3;
            f32x2 vv = u0 + u1;
            float sv = vv.x + vv.y;
            xrow[c * 16] = f2bf(hist_act(sv));
            if (c < 20) {
#pragma unroll
                for (int k2 = 0; k2 < 8; ++k2) { f2a[k2] *= g2a[k2]; g2a[k2] *= E2; }
            }
        }
    }
    __syncthreads();   // xT complete

    // ================= PHASE B: GEMM (A: LDS, B: global; no barriers) ======
    {
        int l = tid & 63, w = tid >> 6;
        int wr = w >> 3, wc = w & 7;                // 2x8 waves; wave tile 16x32
        int lr = l & 15, lk = l >> 4;
        int arow = wr * 16 + lr;
        const char* aBase = (const char*)xT + arow * (XT_STRIDE * 2);

        const ushort* gB = WtF + (((size_t)(sk * 21) * 16 + wc * 2) * 64 + l) * 8;

        f32x4 acc[2];
        acc[0] = (f32x4){0.f, 0.f, 0.f, 0.f};
        acc[1] = (f32x4){0.f, 0.f, 0.f, 0.f};

#pragma unroll
        for (int kt = 0; kt < 21; ++kt) {
            bf16x8 a = *(const bf16x8*)(aBase + kt * 64 + lk * 16);
#pragma unroll
            for (int nt = 0; nt < 2; ++nt) {
                bf16x8 bb = *(const bf16x8*)(gB + ((size_t)kt * 16 + nt) * 512);
                acc[nt] = __builtin_amdgcn_mfma_f32_16x16x32_bf16(a, bb, acc[nt], 0, 0, 0);
            }
        }

        // store partials (bf16): C row=(l>>4)*4+j, col=l&15
        ushort* pp = part + (size_t)sk * PSTR;
        int crow = bm * 32 + wr * 16 + lk * 4;
#pragma unroll
        for (int nt = 0; nt < 2; ++nt) {
            int ccol = wc * 32 + nt * 16 + lr;
#pragma unroll
            for (int j = 0; j < 4; ++j)
                pp[(size_t)(crow + j) * 256 + ccol] = f2bf(acc[nt][j]);
        }
    }
}

// ---------------------------------------------------------------------------
// Kernel 2: split-K reduce (vectorized uint2 part reads) + heads. 128 x 512.
// ---------------------------------------------------------------------------
__global__ __launch_bounds__(512) void k_head(
    const ushort* __restrict__ part,   // [8][2048][256] bf16
    const float* __restrict__ b_flat,
    const float* __restrict__ f_add,
    const float* __restrict__ W_attn,
    const float* __restrict__ b_attn,
    const float* __restrict__ W_fadd,
    const float* __restrict__ b_fadd,
    const float* __restrict__ W_d1,
    const float* __restrict__ b_d1,
    const float* __restrict__ W_d2,
    const float* __restrict__ b_d2,
    const float* __restrict__ wfeat,
    float* __restrict__ out)           // [512]
{
    const int b = blockIdx.x;
    const int tid = threadIdx.x;

    __shared__ float sh1[16 * 256];
    __shared__ float slog[16];
    __shared__ float scomb[256];
    __shared__ float scpart[512];
    __shared__ float r01[8];

    // h1: each thread handles 4 consecutive cols (uint2 = 4 bf16 per sk-plane)
#pragma unroll
    for (int i = 0; i < 2; ++i) {
        int unit = i * 512 + tid;              // [0, 1024)
        int row = unit >> 6, q = unit & 63;    // 16 rows x 64 col-quads
        size_t base = ((size_t)(b * 16 + row) * 256 + q * 4) >> 1; // in uint2-pairs? no: element off
        const ushort* pb0 = part + (size_t)(b * 16 + row) * 256 + q * 4;
        float v0 = b_flat[q * 4 + 0], v1 = b_flat[q * 4 + 1];
        float v2 = b_flat[q * 4 + 2], v3 = b_flat[q * 4 + 3];
        (void)base;
#pragma unroll
        for (int s = 0; s < 8; ++s) {
            uint2 u = *(const uint2*)(pb0 + (size_t)s * PSTR);
            v0 += bf2f((ushort)(u.x & 0xffff));
            v1 += bf2f((ushort)(u.x >> 16));
            v2 += bf2f((ushort)(u.y & 0xffff));
            v3 += bf2f((ushort)(u.y >> 16));
        }
        float4 hv;
        hv.x = fast_tanh(v0); hv.y = fast_tanh(v1);
        hv.z = fast_tanh(v2); hv.w = fast_tanh(v3);
        *(float4*)&sh1[row * 256 + q * 4] = hv;
    }
    __syncthreads();

    if (tid < 256) {
        int ho = tid >> 4, j = tid & 15;
        float sv = 0.f;
#pragma unroll
        for (int t2 = 0; t2 < 16; ++t2)
            sv += sh1[ho * 256 + j + t2 * 16] * W_attn[j + t2 * 16];
        sv += __shfl_xor(sv, 1); sv += __shfl_xor(sv, 2);
        sv += __shfl_xor(sv, 4); sv += __shfl_xor(sv, 8);
        if (j == 0) slog[ho] = sv + b_attn[0];
    }
    __syncthreads();

    if (tid < 256) {
        float attnv[16];
        float mx = -1e30f;
#pragma unroll
        for (int t2 = 0; t2 < 16; ++t2) mx = fmaxf(mx, slog[t2]);
        float sum = 0.f;
#pragma unroll
        for (int t2 = 0; t2 < 16; ++t2) { attnv[t2] = __expf(slog[t2] - mx); sum += attnv[t2]; }
        float inv = __builtin_amdgcn_rcpf(sum);

        float lc = 0.f;
#pragma unroll
        for (int t2 = 0; t2 < 16; ++t2) lc += attnv[t2] * inv * sh1[t2 * 256 + tid];
        lc = fast_tanh(lc);

        float fp = b_fadd[tid];
#pragma unroll
        for (int k = 0; k < 17; ++k) fp += f_add[b * 17 + k] * W_fadd[k * 256 + tid];
        fp = fast_tanh(fp);

        float sg = __builtin_amdgcn_rcpf(1.f + __expf(-wfeat[0]));
        scomb[tid] = (1.f - sg) * fp + sg * lc;
    }
    __syncthreads();

    {
        int n = tid & 255, half = tid >> 8;
        float sc = 0.f;
        int k0 = half * 128;
#pragma unroll 8
        for (int k = 0; k < 128; ++k) sc += scomb[k0 + k] * W_d1[(k0 + k) * 256 + n];
        scpart[half * 256 + n] = sc;
    }
    __syncthreads();

    if (tid < 256) {
        float sc = fast_tanh(scpart[tid] + scpart[256 + tid] + b_d1[tid]);
        float p0 = sc * W_d2[tid * 2 + 0];
        float p1 = sc * W_d2[tid * 2 + 1];
#pragma unroll
        for (int off = 1; off < 64; off <<= 1) {
            p0 += __shfl_xor(p0, off);
            p1 += __shfl_xor(p1, off);
        }
        if ((tid & 63) == 0) { r01[tid >> 6] = p0; r01[4 + (tid >> 6)] = p1; }
    }
    __syncthreads();

    if (tid == 0) {
        float o0 = r01[0] + r01[1] + r01[2] + r01[3] + b_d2[0];
        float o1 = r01[4] + r01[5] + r01[6] + r01[7] + b_d2[1];
        float mx = fmaxf(o0, o1);
        float lse = mx + __logf(__expf(o0 - mx) + __expf(o1 - mx));
        out[b * 2 + 0] = o0 - lse;
        out[b * 2 + 1] = o1 - lse;
        out[256 + b * 2 + 0] = o0;
        out[256 + b * 2 + 1] = o1;
    }
}

// ---------------------------------------------------------------------------
extern "C" void kernel_launch(void* const* d_in, const int* in_sizes, int n_in,
                              void* d_out, int out_size, void* d_ws, size_t ws_size,
                              hipStream_t stream) {
    const float* sim    = (const float*)d_in[0];
    const float* f_add  = (const float*)d_in[1];
    const float* W_flat = (const float*)d_in[2];
    const float* b_flat = (const float*)d_in[3];
    const float* W_attn = (const float*)d_in[4];
    const float* b_attn = (const float*)d_in[5];
    const float* W_fadd = (const float*)d_in[6];
    const float* b_fadd = (const float*)d_in[7];
    const float* W_d1   = (const float*)d_in[8];
    const float* b_d1   = (const float*)d_in[9];
    const float* W_d2   = (const float*)d_in[10];
    const float* b_d2   = (const float*)d_in[11];
    const float* wfeat  = (const float*)d_in[12];
    float* out = (float*)d_out;

    ushort* WtF  = (ushort*)d_ws;                        // 2.75MB fragment-major
    ushort* part = WtF + (size_t)256 * NFLAT;            // [8][2048][256] bf16 (8.4MB)

    hipLaunchKernelGGL(k_prep, dim3(672), dim3(256), 0, stream, W_flat, WtF);
    hipLaunchKernelGGL(k_fused, dim3(512), dim3(1024), XT_BYTES, stream, sim, WtF, part);
    hipLaunchKernelGGL(k_head, dim3(128), dim3(512), 0, stream,
                       part, b_flat, f_add, W_attn, b_attn, W_fadd, b_fadd,
                       W_d1, b_d1, W_d2, b_d2, wfeat, out);
}

// Round 21
// 42.773 us; speedup vs baseline: 1.4460x; 1.0548x over previous
//
#include <hip/hip_runtime.h>
#include <hip/hip_bf16.h>
#include <math.h>

#define BSZ   128
#define NP    16
#define NC    21
#define NH    256
#define HOUT  16
#define NFLAT 5376     // K (permuted layout k' = p*336 + c*16 + wo)

// fused-kernel geometry: block (bm, sk): 32 rows (b = 2bm,2bm+1), K-slice 672
#define XT_STRIDE 680                      // ushorts (672 + 8 pad)
#define XT_BYTES  (32 * XT_STRIDE * 2)     // 43520 -> 2 blocks/CU
#define PSTR      (2048 * 256)             // part per-sk stride (elements)

typedef __attribute__((ext_vector_type(4))) float f32x4;
typedef __attribute__((ext_vector_type(2))) float f32x2;
typedef __attribute__((ext_vector_type(8))) short bf16x8;

__device__ __forceinline__ ushort f2bf(float v) {
    __hip_bfloat16 h = __float2bfloat16(v);
    return *reinterpret_cast<ushort*>(&h);
}

__device__ __forceinline__ float bf2f(ushort u) {
    union { uint i; float f; } cv;
    cv.i = ((uint)u) << 16;
    return cv.f;
}

// tanh(0.01*ln(s)) via odd poly: u in [-0.23, 0.03]; err < 2e-6
__device__ __forceinline__ float hist_act(float s) {
    float u = 0.01f * __logf(fmaxf(s, 1e-10f));
    float u2 = u * u;
    return u * (1.f + u2 * (-0.33333333f + 0.13333333f * u2));
}

// tanh(x) = 1 - 2/(e^{2x}+1)
__device__ __forceinline__ float fast_tanh(float v) {
    float e = __expf(2.f * v);
    return 1.f - 2.f * __builtin_amdgcn_rcpf(e + 1.f);
}

// ---------------------------------------------------------------------------
// Kernel 0: WtF fragment-major B. chunk id = (ks*16 + nt16)*64 + lane covers
//   n = nt16*16 + (l&15), k' = ks*32 + (l>>4)*8 + e  (per-element p/c decode).
// 672 blocks x 256 thr.  (r20-identical)
// ---------------------------------------------------------------------------
__global__ __launch_bounds__(256) void k_prep(const float* __restrict__ W,
                                              ushort* __restrict__ WtF) {
    int id = blockIdx.x * 256 + threadIdx.x;   // [0, 172032)
    int l = id & 63;
    int ks = id >> 10;                         // [0, 168)
    int n = (((id >> 6) & 15) << 4) + (l & 15);
    int kb = ks * 32 + (l >> 4) * 8;
    ushort v[8];
#pragma unroll
    for (int e = 0; e < 8; ++e) {
        int kp = kb + e;                       // k' in [0, 5376)
        int p = kp / 336;
        int rem = kp - p * 336;
        int c = rem >> 4, wo = rem & 15;
        int ksrc = c * 256 + p * 16 + wo;      // original W row
        v[e] = f2bf(W[(size_t)ksrc * NH + n]);
    }
    *(uint4*)(WtF + (size_t)id * 8) = *(uint4*)v;
}

// ---------------------------------------------------------------------------
// Kernel 1 (fused): RBF (packed-f32) -> 1 barrier
//                   -> GEMM (32x16 wave tile: 1 B-load + 2 A ds_reads / kt).
// 512 blocks (bm = bid>>3, sk = bid&7) x 1024 thr, 43.5 KB LDS, 2 blocks/CU.
// (r20 structure; only the GEMM wave tile changed 16x32 -> 32x16)
// ---------------------------------------------------------------------------
extern "C" __global__ __launch_bounds__(1024, 8) void k_fused(
    const float* __restrict__ sim,     // [128][16][64][64]
    const ushort* __restrict__ WtF,    // fragment-major
    ushort* __restrict__ part)         // [8][2048][256] bf16
{
    extern __shared__ __align__(16) char smem[];
    ushort* xT = (ushort*)smem;                       // [32][XT_STRIDE]
    const int bid = blockIdx.x;
    const int bm = bid >> 3, sk = bid & 7;
    const int tid = threadIdx.x;

    // ================= PHASE A: RBF (1 task/thread, packed f32) ============
    {
        int w = tid >> 6, l = tid & 63;
        int tile = w >> 2, q = w & 3;                // 4 sim tiles, ho-quad q
        int boff = tile >> 1, poff = tile & 1;
        int wo = l & 15, ho = q * 4 + (l >> 4);

        const float* src = sim
            + (((size_t)(2 * bm + boff)) * 16 + (2 * sk + poff)) * 4096
            + (size_t)(ho * 4) * 64 + wo * 4;
        float4 ebuf[4];
#pragma unroll
        for (int i = 0; i < 4; ++i) ebuf[i] = *(const float4*)(src + i * 64);

        f32x2 f2a[8], g2a[8];
        float s0[4];
#pragma unroll
        for (int i = 0; i < 4; ++i) {
            float4 e4 = ebuf[i];
            float pa = 0.f, pb = 0.f;
#pragma unroll
            for (int jj = 0; jj < 4; ++jj) {
                float e = (jj == 0) ? e4.x : (jj == 1) ? e4.y : (jj == 2) ? e4.z : e4.w;
                float d0 = e - 1.0f;
                float t0 = __expf(-50.f * d0 * d0);
                if (jj & 1) pb += t0; else pa += t0;
                float d1 = e - 0.95f;
                float fv = __expf(-50.f * d1 * d1);
                float gv = __expf(-10.f * d1 - 0.5f);
                int k2 = i * 4 + jj;
                if (k2 & 1) { f2a[k2 >> 1].y = fv; g2a[k2 >> 1].y = gv; }
                else        { f2a[k2 >> 1].x = fv; g2a[k2 >> 1].x = gv; }
            }
            s0[i] = pa + pb;
        }
        float sum0 = (s0[0] + s0[1]) + (s0[2] + s0[3]);
        ushort* xrow = xT + (boff * 16 + ho) * XT_STRIDE + poff * 336 + wo;
        xrow[0] = f2bf(hist_act(sum0));

        const f32x2 E2 = {0.36787944117f, 0.36787944117f};
#pragma unroll
        for (int c = 1; c < 21; ++c) {
            f32x2 t0 = f2a[0] + f2a[1], t1 = f2a[2] + f2a[3];
            f32x2 t2 = f2a[4] + f2a[5], t3 = f2a[6] + f2a[7];
            f32x2 u0 = t0 + t1, u1 = t2 + t3;
            f32x2 vv = u0 + u1;
            float sv = vv.x + vv.y;
            xrow[c * 16] = f2bf(hist_act(sv));
            if (c < 20) {
#pragma unroll
                for (int k2 = 0; k2 < 8; ++k2) { f2a[k2] *= g2a[k2]; g2a[k2] *= E2; }
            }
        }
    }
    __syncthreads();   // xT complete

    // ================= PHASE B: GEMM, 32x16 wave tile, 0 barriers ==========
    {
        int l = tid & 63, w = tid >> 6;              // w = nt16 (0..15)
        int lr = l & 15, lk = l >> 4;
        const char* aBase0 = (const char*)xT + lr * (XT_STRIDE * 2);
        const char* aBase1 = (const char*)xT + (16 + lr) * (XT_STRIDE * 2);

        const ushort* gB = WtF + (((size_t)(sk * 21) * 16 + w) * 64 + l) * 8;

        f32x4 acc0 = (f32x4){0.f, 0.f, 0.f, 0.f};
        f32x4 acc1 = (f32x4){0.f, 0.f, 0.f, 0.f};

#pragma unroll
        for (int kt = 0; kt < 21; ++kt) {
            bf16x8 bb = *(const bf16x8*)(gB + (size_t)kt * 8192);
            bf16x8 a0 = *(const bf16x8*)(aBase0 + kt * 64 + lk * 16);
            bf16x8 a1 = *(const bf16x8*)(aBase1 + kt * 64 + lk * 16);
            acc0 = __builtin_amdgcn_mfma_f32_16x16x32_bf16(a0, bb, acc0, 0, 0, 0);
            acc1 = __builtin_amdgcn_mfma_f32_16x16x32_bf16(a1, bb, acc1, 0, 0, 0);
        }

        // store partials (bf16): C row=(l>>4)*4+j, col=l&15
        ushort* pp = part + (size_t)sk * PSTR;
        int ccol = w * 16 + lr;
        int crow0 = bm * 32 + lk * 4;
#pragma unroll
        for (int j = 0; j < 4; ++j) {
            pp[(size_t)(crow0 + j) * 256 + ccol] = f2bf(acc0[j]);
            pp[(size_t)(crow0 + 16 + j) * 256 + ccol] = f2bf(acc1[j]);
        }
    }
}

// ---------------------------------------------------------------------------
// Kernel 2: split-K reduce (vectorized uint2 part reads) + heads. 128 x 512.
// (r20-identical)
// ---------------------------------------------------------------------------
__global__ __launch_bounds__(512) void k_head(
    const ushort* __restrict__ part,   // [8][2048][256] bf16
    const float* __restrict__ b_flat,
    const float* __restrict__ f_add,
    const float* __restrict__ W_attn,
    const float* __restrict__ b_attn,
    const float* __restrict__ W_fadd,
    const float* __restrict__ b_fadd,
    const float* __restrict__ W_d1,
    const float* __restrict__ b_d1,
    const float* __restrict__ W_d2,
    const float* __restrict__ b_d2,
    const float* __restrict__ wfeat,
    float* __restrict__ out)           // [512]
{
    const int b = blockIdx.x;
    const int tid = threadIdx.x;

    __shared__ float sh1[16 * 256];
    __shared__ float slog[16];
    __shared__ float scomb[256];
    __shared__ float scpart[512];
    __shared__ float r01[8];

#pragma unroll
    for (int i = 0; i < 2; ++i) {
        int unit = i * 512 + tid;              // [0, 1024)
        int row = unit >> 6, q = unit & 63;    // 16 rows x 64 col-quads
        const ushort* pb0 = part + (size_t)(b * 16 + row) * 256 + q * 4;
        float v0 = b_flat[q * 4 + 0], v1 = b_flat[q * 4 + 1];
        float v2 = b_flat[q * 4 + 2], v3 = b_flat[q * 4 + 3];
#pragma unroll
        for (int s = 0; s < 8; ++s) {
            uint2 u = *(const uint2*)(pb0 + (size_t)s * PSTR);
            v0 += bf2f((ushort)(u.x & 0xffff));
            v1 += bf2f((ushort)(u.x >> 16));
            v2 += bf2f((ushort)(u.y & 0xffff));
            v3 += bf2f((ushort)(u.y >> 16));
        }
        float4 hv;
        hv.x = fast_tanh(v0); hv.y = fast_tanh(v1);
        hv.z = fast_tanh(v2); hv.w = fast_tanh(v3);
        *(float4*)&sh1[row * 256 + q * 4] = hv;
    }
    __syncthreads();

    if (tid < 256) {
        int ho = tid >> 4, j = tid & 15;
        float sv = 0.f;
#pragma unroll
        for (int t2 = 0; t2 < 16; ++t2)
            sv += sh1[ho * 256 + j + t2 * 16] * W_attn[j + t2 * 16];
        sv += __shfl_xor(sv, 1); sv += __shfl_xor(sv, 2);
        sv += __shfl_xor(sv, 4); sv += __shfl_xor(sv, 8);
        if (j == 0) slog[ho] = sv + b_attn[0];
    }
    __syncthreads();

    if (tid < 256) {
        float attnv[16];
        float mx = -1e30f;
#pragma unroll
        for (int t2 = 0; t2 < 16; ++t2) mx = fmaxf(mx, slog[t2]);
        float sum = 0.f;
#pragma unroll
        for (int t2 = 0; t2 < 16; ++t2) { attnv[t2] = __expf(slog[t2] - mx); sum += attnv[t2]; }
        float inv = __builtin_amdgcn_rcpf(sum);

        float lc = 0.f;
#pragma unroll
        for (int t2 = 0; t2 < 16; ++t2) lc += attnv[t2] * inv * sh1[t2 * 256 + tid];
        lc = fast_tanh(lc);

        float fp = b_fadd[tid];
#pragma unroll
        for (int k = 0; k < 17; ++k) fp += f_add[b * 17 + k] * W_fadd[k * 256 + tid];
        fp = fast_tanh(fp);

        float sg = __builtin_amdgcn_rcpf(1.f + __expf(-wfeat[0]));
        scomb[tid] = (1.f - sg) * fp + sg * lc;
    }
    __syncthreads();

    {
        int n = tid & 255, half = tid >> 8;
        float sc = 0.f;
        int k0 = half * 128;
#pragma unroll 8
        for (int k = 0; k < 128; ++k) sc += scomb[k0 + k] * W_d1[(k0 + k) * 256 + n];
        scpart[half * 256 + n] = sc;
    }
    __syncthreads();

    if (tid < 256) {
        float sc = fast_tanh(scpart[tid] + scpart[256 + tid] + b_d1[tid]);
        float p0 = sc * W_d2[tid * 2 + 0];
        float p1 = sc * W_d2[tid * 2 + 1];
#pragma unroll
        for (int off = 1; off < 64; off <<= 1) {
            p0 += __shfl_xor(p0, off);
            p1 += __shfl_xor(p1, off);
        }
        if ((tid & 63) == 0) { r01[tid >> 6] = p0; r01[4 + (tid >> 6)] = p1; }
    }
    __syncthreads();

    if (tid == 0) {
        float o0 = r01[0] + r01[1] + r01[2] + r01[3] + b_d2[0];
        float o1 = r01[4] + r01[5] + r01[6] + r01[7] + b_d2[1];
        float mx = fmaxf(o0, o1);
        float lse = mx + __logf(__expf(o0 - mx) + __expf(o1 - mx));
        out[b * 2 + 0] = o0 - lse;
        out[b * 2 + 1] = o1 - lse;
        out[256 + b * 2 + 0] = o0;
        out[256 + b * 2 + 1] = o1;
    }
}

// ---------------------------------------------------------------------------
extern "C" void kernel_launch(void* const* d_in, const int* in_sizes, int n_in,
                              void* d_out, int out_size, void* d_ws, size_t ws_size,
                              hipStream_t stream) {
    const float* sim    = (const float*)d_in[0];
    const float* f_add  = (const float*)d_in[1];
    const float* W_flat = (const float*)d_in[2];
    const float* b_flat = (const float*)d_in[3];
    const float* W_attn = (const float*)d_in[4];
    const float* b_attn = (const float*)d_in[5];
    const float* W_fadd = (const float*)d_in[6];
    const float* b_fadd = (const float*)d_in[7];
    const float* W_d1   = (const float*)d_in[8];
    const float* b_d1   = (const float*)d_in[9];
    const float* W_d2   = (const float*)d_in[10];
    const float* b_d2   = (const float*)d_in[11];
    const float* wfeat  = (const float*)d_in[12];
    float* out = (float*)d_out;

    ushort* WtF  = (ushort*)d_ws;                        // 2.75MB fragment-major
    ushort* part = WtF + (size_t)256 * NFLAT;            // [8][2048][256] bf16 (8.4MB)

    hipLaunchKernelGGL(k_prep, dim3(672), dim3(256), 0, stream, W_flat, WtF);
    hipLaunchKernelGGL(k_fused, dim3(512), dim3(1024), XT_BYTES, stream, sim, WtF, part);
    hipLaunchKernelGGL(k_head, dim3(128), dim3(512), 0, stream,
                       part, b_flat, f_add, W_attn, b_attn, W_fadd, b_fadd,
                       W_d1, b_d1, W_d2, b_d2, wfeat, out);
}